// Round 2
// baseline (859.992 us; speedup 1.0000x reference)
//
#include <hip/hip_runtime.h>
#include <cmath>

#define NUM_LEVELS 16
#define GRID_CH 66
#define BLOCK 256

struct Params {
    int   offset[NUM_LEVELS];
    int   res_eff[NUM_LEVELS];
    int   use_hash[NUM_LEVELS];
    float scale[NUM_LEVELS];
};

static Params make_params() {
    Params p;
    long long off = 0;
    const double S = std::log2(2048.0 / 16.0) / 15.0;   // 7/15
    for (int l = 0; l < NUM_LEVELS; ++l) {
        double scale = std::exp2((double)l * S) * 16.0 - 1.0;
        int resolution = (int)std::ceil(scale) + 1;
        int res_eff = resolution + 1;                    // ALIGN_CORNERS = False
        long long cube = (long long)res_eff * res_eff * res_eff;
        long long n = cube < 131072 ? cube : 131072;     // min(2^17, res_eff^3)
        n = ((n + 7) / 8) * 8;
        p.offset[l]  = (int)off;
        p.res_eff[l] = res_eff;
        p.use_hash[l] = (cube > n) ? 1 : 0;
        p.scale[l]   = (float)scale;
        off += n;
    }
    return p;
}
static const Params g_params = make_params();

// 8-byte pair with 4-byte alignment guarantee (channel index may be odd).
struct __attribute__((packed, aligned(4))) F2 { float x, y; };

__global__ __launch_bounds__(BLOCK) void tge_kernel(
    const float* __restrict__ inputs,   // [B,3]
    const float* __restrict__ tri,      // [B,8]
    const float* __restrict__ emb,      // [TABLE_ROWS*66]
    float* __restrict__ out,            // [B,32]
    Params P)
{
    const int l = blockIdx.y;                          // level (block-uniform)
    const int i = blockIdx.x * BLOCK + threadIdx.x;    // sample

    // per-sample inputs
    const float x = inputs[i * 3 + 0];
    const float y = inputs[i * 3 + 1];
    const float z = inputs[i * 3 + 2];
    const float4 t0 = *reinterpret_cast<const float4*>(tri + (size_t)i * 8);
    const float4 t1 = *reinterpret_cast<const float4*>(tri + (size_t)i * 8 + 4);
    const float wa0 = t0.x, wb0 = t0.z, wa1 = t1.x, wb1 = t1.z;
    const int   ia0 = (int)t0.y, ia1 = (int)t1.y;

    // Channel-pair geometry: ib == (ia+1) % 66 by construction.
    // base = min(ia,64) so the float2 never reads past channel 65 (avoids
    // 4-byte OOB past the last table row). hi => ia==65 (wrap case).
    const int  base0 = ia0 < 64 ? ia0 : 64;
    const int  base1 = ia1 < 64 ? ia1 : 64;
    const bool hi0 = (ia0 == 65);
    const bool hi1 = (ia1 == 65);

    const float scale   = P.scale[l];
    const int   off     = P.offset[l];
    const int   R       = P.res_eff[l];
    const bool  use_hash = P.use_hash[l] != 0;

    // position / fractional part (matches reference f32 order)
    const float px = x * scale + 0.5f;
    const float py = y * scale + 0.5f;
    const float pz = z * scale + 0.5f;
    const float fx = floorf(px), fy = floorf(py), fz = floorf(pz);
    const float rx = px - fx, ry = py - fy, rz = pz - fz;
    const unsigned ux = (unsigned)fx, uy = (unsigned)fy, uz = (unsigned)fz;

    // per-dimension index contributions for both corner offsets
    unsigned hx0, hx1, hy0, hy1, hz0, hz1;
    if (use_hash) {
        hx0 = ux;                   hx1 = ux + 1u;                     // prime 1
        hy0 = uy * 2654435761u;     hy1 = (uy + 1u) * 2654435761u;
        hz0 = uz * 805459861u;      hz1 = (uz + 1u) * 805459861u;
    } else {
        hx0 = ux;                   hx1 = ux + 1u;
        hy0 = uy * (unsigned)R;     hy1 = (uy + 1u) * (unsigned)R;
        hz0 = uz * (unsigned)(R*R); hz1 = (uz + 1u) * (unsigned)(R*R);
    }

    // All 8 corner rows, then all 16 pair loads issued before any use (MLP).
    const float* rows[8];
    #pragma unroll
    for (int c = 0; c < 8; ++c) {
        const unsigned a = (c & 1) ? hx1 : hx0;
        const unsigned b = (c & 2) ? hy1 : hy0;
        const unsigned d = (c & 4) ? hz1 : hz0;
        const unsigned idx = use_hash ? ((a ^ b ^ d) & 131071u) : (a + b + d);
        rows[c] = emb + (size_t)(off + (int)idx) * GRID_CH;
    }

    F2 p0[8], p1[8];
    #pragma unroll
    for (int c = 0; c < 8; ++c) {
        p0[c] = *reinterpret_cast<const F2*>(rows[c] + base0);
        p1[c] = *reinterpret_cast<const F2*>(rows[c] + base1);
    }

    // vb channel: normally pair.y; wrap (ia==65) takes channel 0 of the row.
    float q0[8], q1[8];
    #pragma unroll
    for (int c = 0; c < 8; ++c) { q0[c] = p0[c].y; q1[c] = p1[c].y; }
    if (hi0) {
        #pragma unroll
        for (int c = 0; c < 8; ++c) q0[c] = rows[c][0];
    }
    if (hi1) {
        #pragma unroll
        for (int c = 0; c < 8; ++c) q1[c] = rows[c][0];
    }

    const float w0x = 1.f - rx, w1x = rx;
    const float w0y = 1.f - ry, w1y = ry;
    const float w0z = 1.f - rz, w1z = rz;

    float acc0 = 0.f, acc1 = 0.f;
    #pragma unroll
    for (int c = 0; c < 8; ++c) {
        const float va0 = hi0 ? p0[c].y : p0[c].x;
        const float va1 = hi1 ? p1[c].y : p1[c].x;
        const float vb0 = q0[c];
        const float vb1 = q1[c];
        const float wx = (c & 1) ? w1x : w0x;
        const float wy = (c & 2) ? w1y : w0y;
        const float wz = (c & 4) ? w1z : w0z;
        const float w = wx * wy * wz;
        acc0 += w * (wa0 * va0 + wb0 * vb0);
        acc1 += w * (wa1 * va1 + wb1 * vb1);
    }

    *reinterpret_cast<float2*>(out + (size_t)i * 32 + 2 * l) = make_float2(acc0, acc1);
}

extern "C" void kernel_launch(void* const* d_in, const int* in_sizes, int n_in,
                              void* d_out, int out_size, void* d_ws, size_t ws_size,
                              hipStream_t stream) {
    const float* inputs = (const float*)d_in[0];
    const float* tri    = (const float*)d_in[1];
    const float* emb    = (const float*)d_in[2];
    float* out          = (float*)d_out;

    const int B = in_sizes[0] / 3;           // 262144
    dim3 grid(B / BLOCK, NUM_LEVELS, 1);
    tge_kernel<<<grid, BLOCK, 0, stream>>>(inputs, tri, emb, out, g_params);
}

// Round 3
// 766.100 us; speedup vs baseline: 1.1226x; 1.1226x over previous
//
#include <hip/hip_runtime.h>
#include <cmath>

#define NUM_LEVELS 16
#define GRID_CH 66
#define BLOCK 256
#define LDS_STRIDE 33   // 32 output channels + 1 pad (bank-conflict-free)

struct Params {
    int   offset[NUM_LEVELS];
    int   res_eff[NUM_LEVELS];
    int   use_hash[NUM_LEVELS];
    float scale[NUM_LEVELS];
};

static Params make_params() {
    Params p;
    long long off = 0;
    const double S = std::log2(2048.0 / 16.0) / 15.0;   // 7/15
    for (int l = 0; l < NUM_LEVELS; ++l) {
        double scale = std::exp2((double)l * S) * 16.0 - 1.0;
        int resolution = (int)std::ceil(scale) + 1;
        int res_eff = resolution + 1;                    // ALIGN_CORNERS = False
        long long cube = (long long)res_eff * res_eff * res_eff;
        long long n = cube < 131072 ? cube : 131072;     // min(2^17, res_eff^3)
        n = ((n + 7) / 8) * 8;
        p.offset[l]  = (int)off;
        p.res_eff[l] = res_eff;
        p.use_hash[l] = (cube > n) ? 1 : 0;
        p.scale[l]   = (float)scale;
        off += n;
    }
    return p;
}
static const Params g_params = make_params();

// One thread per sample; loop over all 16 levels INSIDE the thread so the
// whole (fully-resident) grid phases through levels together -> the active
// hash table (34.6 MB) stays L3-resident and re-touches don't hit HBM.
__global__ __launch_bounds__(BLOCK, 4) void tge_kernel(
    const float* __restrict__ inputs,   // [B,3]
    const float* __restrict__ tri,      // [B,8]
    const float* __restrict__ emb,      // [TABLE_ROWS*66]
    float* __restrict__ out,            // [B,32]
    Params P)
{
    __shared__ float sout[BLOCK * LDS_STRIDE];

    const int t = threadIdx.x;
    const int i = blockIdx.x * BLOCK + t;    // sample

    // per-sample inputs (loaded once for all 16 levels)
    const float x = inputs[i * 3 + 0];
    const float y = inputs[i * 3 + 1];
    const float z = inputs[i * 3 + 2];
    const float4 t0 = *reinterpret_cast<const float4*>(tri + (size_t)i * 8);
    const float4 t1 = *reinterpret_cast<const float4*>(tri + (size_t)i * 8 + 4);
    const float wa0 = t0.x, wb0 = t0.z, wa1 = t1.x, wb1 = t1.z;
    const int   ia0 = (int)t0.y, ib0 = (int)t0.w;
    const int   ia1 = (int)t1.y, ib1 = (int)t1.w;

    #pragma unroll 1
    for (int l = 0; l < NUM_LEVELS; ++l) {
        const float scale    = P.scale[l];
        const int   off      = P.offset[l];
        const int   R        = P.res_eff[l];
        const bool  use_hash = P.use_hash[l] != 0;

        // position / fractional part (matches reference f32 order)
        const float px = x * scale + 0.5f;
        const float py = y * scale + 0.5f;
        const float pz = z * scale + 0.5f;
        const float fx = floorf(px), fy = floorf(py), fz = floorf(pz);
        const float rx = px - fx, ry = py - fy, rz = pz - fz;
        const unsigned ux = (unsigned)fx, uy = (unsigned)fy, uz = (unsigned)fz;

        // per-dimension index contributions for both corner offsets
        unsigned hx0, hx1, hy0, hy1, hz0, hz1;
        if (use_hash) {
            hx0 = ux;                   hx1 = ux + 1u;                     // prime 1
            hy0 = uy * 2654435761u;     hy1 = (uy + 1u) * 2654435761u;
            hz0 = uz * 805459861u;      hz1 = (uz + 1u) * 805459861u;
        } else {
            hx0 = ux;                   hx1 = ux + 1u;
            hy0 = uy * (unsigned)R;     hy1 = (uy + 1u) * (unsigned)R;
            hz0 = uz * (unsigned)(R*R); hz1 = (uz + 1u) * (unsigned)(R*R);
        }

        const float w0x = 1.f - rx, w1x = rx;
        const float w0y = 1.f - ry, w1y = ry;
        const float w0z = 1.f - rz, w1z = rz;

        float acc0 = 0.f, acc1 = 0.f;
        #pragma unroll
        for (int c = 0; c < 8; ++c) {
            const unsigned a = (c & 1) ? hx1 : hx0;
            const unsigned b = (c & 2) ? hy1 : hy0;
            const unsigned d = (c & 4) ? hz1 : hz0;
            const unsigned idx = use_hash ? ((a ^ b ^ d) & 131071u) : (a + b + d);
            const float* rowp = emb + (size_t)(off + (int)idx) * GRID_CH;
            const float va0 = rowp[ia0];
            const float vb0 = rowp[ib0];
            const float va1 = rowp[ia1];
            const float vb1 = rowp[ib1];
            const float wx = (c & 1) ? w1x : w0x;
            const float wy = (c & 2) ? w1y : w0y;
            const float wz = (c & 4) ? w1z : w0z;
            const float w = wx * wy * wz;
            acc0 += w * (wa0 * va0 + wb0 * vb0);
            acc1 += w * (wa1 * va1 + wb1 * vb1);
        }

        sout[t * LDS_STRIDE + 2 * l]     = acc0;
        sout[t * LDS_STRIDE + 2 * l + 1] = acc1;
    }

    __syncthreads();

    // Coalesced block output: 8192 consecutive floats per block, float4 each.
    const size_t obase = (size_t)blockIdx.x * (BLOCK * 32);
    #pragma unroll
    for (int j = 0; j < 8; ++j) {
        const int g = t * 4 + j * 1024;          // local flat float index
        const int s = g >> 5;                    // sample-in-block
        const int c = g & 31;                    // channel (0..28, step 4)
        const float* p = sout + s * LDS_STRIDE + c;
        float4 v = make_float4(p[0], p[1], p[2], p[3]);
        *reinterpret_cast<float4*>(out + obase + g) = v;
    }
}

extern "C" void kernel_launch(void* const* d_in, const int* in_sizes, int n_in,
                              void* d_out, int out_size, void* d_ws, size_t ws_size,
                              hipStream_t stream) {
    const float* inputs = (const float*)d_in[0];
    const float* tri    = (const float*)d_in[1];
    const float* emb    = (const float*)d_in[2];
    float* out          = (float*)d_out;

    const int B = in_sizes[0] / 3;           // 262144
    dim3 grid(B / BLOCK, 1, 1);
    tge_kernel<<<grid, BLOCK, 0, stream>>>(inputs, tri, emb, out, g_params);
}